// Round 10
// baseline (222.417 us; speedup 1.0000x reference)
//
#include <hip/hip_runtime.h>
#include <float.h>
#include <math.h>

#define B_SZ   2048
#define D_DIM  256
#define P_DIM  4
#define N_TOT  4096        // 2*B
#define EPS_F  1e-8f
#define NB     512         // buckets over ld in [0,4): width 1/128
#define BSCALE 128.0f

typedef short  s16x8 __attribute__((ext_vector_type(8)));
typedef float  f32x4 __attribute__((ext_vector_type(4)));

__device__ __forceinline__ void async_load16(const void* g, const void* l) {
    __builtin_amdgcn_global_load_lds(
        (const __attribute__((address_space(1))) unsigned int*)g,
        (__attribute__((address_space(3))) unsigned int*)l,
        16, 0, 0);
}

__device__ __forceinline__ unsigned short f2bf(float x) {
    unsigned int b = __float_as_uint(x);
    b += 0x7FFFu + ((b >> 16) & 1u);        // RNE
    return (unsigned short)(b >> 16);
}

// ---------------- Kernel A: row-normalize features -> bf16 ----------------
__global__ __launch_bounds__(64) void normalize_kernel(
    const float* __restrict__ z_i, const float* __restrict__ z_j,
    unsigned short* __restrict__ fb)
{
    int row  = blockIdx.x;
    int lane = threadIdx.x;
    const float* src = (row < B_SZ) ? (z_i + (size_t)row * D_DIM)
                                    : (z_j + (size_t)(row - B_SZ) * D_DIM);
    float4 v = ((const float4*)src)[lane];
    float ss = v.x*v.x + v.y*v.y + v.z*v.z + v.w*v.w;
    #pragma unroll
    for (int off = 32; off > 0; off >>= 1)
        ss += __shfl_down(ss, off, 64);
    ss = __shfl(ss, 0, 64);
    float inv = 1.0f / sqrtf(ss);
    ushort4 o;
    o.x = f2bf(v.x * inv); o.y = f2bf(v.y * inv);
    o.z = f2bf(v.z * inv); o.w = f2bf(v.w * inv);
    ((ushort4*)(fb + (size_t)row * D_DIM))[lane] = o;
}

// ---- Fused kernel: 16 rows/block; MFMA logits + histogram CDF, no logits in HBM ----
// Waves 0-3: stage B chunks (64 cols x 256 k, dbuf) + MFMA (A in registers).
// Waves 4-7: epilogue of previous chunk (exp, L1-dist bucket, LDS-atomic hists).
// Then per-row suffix scan + sum_b cnt[b]*log(S[b]) fully in-wave.
#define PHYS4(j) (*(const float4*)(((j) < B_SZ) ? (physics_i + (size_t)(j) * 4) \
                                                : (physics_j + (size_t)((j) - B_SZ) * 4)))

__global__ __launch_bounds__(512, 2) void fused_kernel(
    const unsigned short* __restrict__ fb,
    const float* __restrict__ physics_i, const float* __restrict__ physics_j,
    float* __restrict__ rowres)
{
    __shared__ unsigned short Atile[16 * 256];      // 8 KB
    __shared__ unsigned short Btile[2][64 * 256];   // 64 KB (dbuf) [col][k]
    __shared__ float    accb[2][4][256];            // 8 KB acc handoff (dbuf)
    __shared__ float    bs[16][NB];                 // 32 KB e-sum hists
    __shared__ unsigned cw[16][NB / 2];             // 16 KB packed u16 count hists
    __shared__ float    scr[64];                    // sum_lo partials [epiwave][row]

    const int tid   = threadIdx.x;
    const int w     = tid >> 6;                     // wave 0..7
    const int L     = tid & 63;
    const int lane  = L;
    const int rowg0 = blockIdx.x * 16;

    // issue A staging: 8 waves x 1 KB, linear (rows rowg0..rowg0+15)
    async_load16(fb + (size_t)rowg0 * D_DIM + w * 512 + L * 8,
                 Atile + w * 512 + L * 8);
    // issue B chunk-0 staging: gemm waves, 8 x 1 KB each (cols 0..63)
    if (w < 4) {
        #pragma unroll
        for (int k = 0; k < 8; ++k)
            async_load16(fb + (size_t)w * 4096 + k * 512 + L * 8,
                         &Btile[0][w * 4096 + k * 512 + L * 8]);
    }
    // zero histograms
    #pragma unroll
    for (int t = 0; t < 16; ++t) ((float*)bs)[tid + t * 512] = 0.f;
    #pragma unroll
    for (int t = 0; t < 8; ++t)  ((unsigned*)cw)[tid + t * 512] = 0u;
    __syncthreads();                                // A + B0 staged, zeros visible

    // gemm waves: A fragments to registers (held whole kernel)
    s16x8 afr[8];
    if (w < 4) {
        #pragma unroll
        for (int ks = 0; ks < 8; ++ks)
            afr[ks] = *(const s16x8*)&Atile[(L & 15) * 256 + ks * 32 + (L >> 4) * 8];
    }
    // epilogue waves: anchor labels for their 4 rows
    float4 Li4[4];
    float  sl[4] = {0.f, 0.f, 0.f, 0.f};
    if (w >= 4) {
        #pragma unroll
        for (int q = 0; q < 4; ++q)
            Li4[q] = PHYS4(rowg0 + (L >> 4) * 4 + q);
    }

#define EPILOGUE(PC)                                                          \
    {                                                                         \
        int we = w - 4;                                                       \
        f32x4 a4 = *(const f32x4*)&accb[(PC) & 1][we][L * 4];                 \
        int colg = (PC) * 64 + we * 16 + (L & 15);                            \
        float4 Lj = PHYS4(colg);                                              \
        int rbase = (L >> 4) * 4;                                             \
        _Pragma("unroll")                                                     \
        for (int q = 0; q < 4; ++q) {                                         \
            float l = a4[q] * 0.5f;                    /* /TEMPERATURE */     \
            if (colg != rowg0 + rbase + q) {                                  \
                float d = fabsf(Li4[q].x - Lj.x) + fabsf(Li4[q].y - Lj.y)     \
                        + fabsf(Li4[q].z - Lj.z) + fabsf(Li4[q].w - Lj.w);    \
                int b = (int)(d * BSCALE); if (b > NB - 1) b = NB - 1;        \
                atomicAdd(&bs[rbase + q][b], __expf(l));                      \
                atomicAdd(&cw[rbase + q][b >> 1], 1u << ((b & 1) * 16));      \
                sl[q] += l;                                                   \
            }                                                                 \
        }                                                                     \
    }

    for (int c = 0; c < 64; ++c) {
        if (w < 4) {
            int buf = c & 1;
            if (c + 1 < 64) {                       // prefetch next B chunk
                const unsigned short* gb = fb + (size_t)(c + 1) * 64 * D_DIM;
                #pragma unroll
                for (int k = 0; k < 8; ++k)
                    async_load16(gb + w * 4096 + k * 512 + L * 8,
                                 &Btile[buf ^ 1][w * 4096 + k * 512 + L * 8]);
            }
            f32x4 acc = {0.f, 0.f, 0.f, 0.f};
            #pragma unroll
            for (int ks = 0; ks < 8; ++ks) {
                s16x8 bfr = *(const s16x8*)
                    &Btile[buf][(w * 16 + (L & 15)) * 256 + ks * 32 + (L >> 4) * 8];
                acc = __builtin_amdgcn_mfma_f32_16x16x32_bf16(afr[ks], bfr, acc, 0, 0, 0);
            }
            *(f32x4*)&accb[buf][w][L * 4] = acc;
        } else if (c > 0) {
            EPILOGUE(c - 1);
        }
        __syncthreads();
    }
    if (w >= 4) {
        EPILOGUE(63);
        // reduce sum_lo within 16-lane groups (rows = quad*4+q), store partials
        #pragma unroll
        for (int off = 8; off > 0; off >>= 1) {
            #pragma unroll
            for (int q = 0; q < 4; ++q) sl[q] += __shfl_down(sl[q], off, 16);
        }
        if ((L & 15) == 0) {
            #pragma unroll
            for (int q = 0; q < 4; ++q)
                scr[(w - 4) * 16 + (L >> 4) * 4 + q] = sl[q];
        }
    }
    __syncthreads();                                // hists + scr complete

    // per-row suffix scan + logsum; wave w handles rows 2w, 2w+1
    #pragma unroll
    for (int rr = 0; rr < 2; ++rr) {
        int row = w * 2 + rr;
        float v[8], T[8];
        #pragma unroll
        for (int j = 0; j < 8; ++j) v[j] = bs[row][j * 64 + lane];
        #pragma unroll
        for (int j = 0; j < 8; ++j) {
            float s = v[j];
            #pragma unroll
            for (int off = 1; off < 64; off <<= 1) {
                float u = __shfl_down(s, off, 64);
                if (lane + off < 64) s += u;
            }
            v[j] = s;                               // in-wave inclusive suffix
            T[j] = __shfl(s, 0, 64);                // slice total
        }
        float hi = 0.f, logsum = 0.f;
        #pragma unroll
        for (int j = 7; j >= 0; --j) {
            float S = v[j] + hi;                    // inclusive suffix at bucket j*64+lane
            hi += T[j];
            unsigned cword = cw[row][j * 32 + (lane >> 1)];
            float cnt = (float)((cword >> ((lane & 1) * 16)) & 0xFFFFu);
            logsum = fmaf(cnt, __logf(S + EPS_F), logsum);
        }
        #pragma unroll
        for (int off = 32; off > 0; off >>= 1)
            logsum += __shfl_down(logsum, off, 64);
        if (lane == 0) {
            float slo = scr[row] + scr[16 + row] + scr[32 + row] + scr[48 + row];
            rowres[rowg0 + row] = logsum - slo;
        }
    }
#undef EPILOGUE
}

// ---------------- Kernel D: final reduce ----------------
__global__ __launch_bounds__(256) void final_kernel(
    const float* __restrict__ rowres, float* __restrict__ out)
{
    __shared__ float red[4];
    int tid = threadIdx.x;
    float s = 0.f;
    for (int i = tid; i < N_TOT; i += 256) s += rowres[i];
    #pragma unroll
    for (int off = 32; off > 0; off >>= 1)
        s += __shfl_down(s, off, 64);
    if ((tid & 63) == 0) red[tid >> 6] = s;
    __syncthreads();
    if (tid == 0) {
        double tot = (double)red[0] + red[1] + red[2] + red[3];
        out[0] = (float)(tot / ((double)N_TOT * (N_TOT - 1)));
    }
}

extern "C" void kernel_launch(void* const* d_in, const int* in_sizes, int n_in,
                              void* d_out, int out_size, void* d_ws, size_t ws_size,
                              hipStream_t stream)
{
    const float* z_i  = (const float*)d_in[0];
    const float* z_j  = (const float*)d_in[1];
    const float* ph_i = (const float*)d_in[2];
    const float* ph_j = (const float*)d_in[3];

    unsigned short* fb     = (unsigned short*)d_ws;                 // 2 MB bf16
    float*          rowres = (float*)(fb + (size_t)N_TOT * D_DIM);  // 16 KB

    normalize_kernel<<<N_TOT, 64, 0, stream>>>(z_i, z_j, fb);
    fused_kernel<<<N_TOT / 16, 512, 0, stream>>>(fb, ph_i, ph_j, rowres);
    final_kernel<<<1, 256, 0, stream>>>(rowres, (float*)d_out);
}

// Round 11
// 200.661 us; speedup vs baseline: 1.1084x; 1.1084x over previous
//
#include <hip/hip_runtime.h>
#include <float.h>
#include <math.h>

#define B_SZ   2048
#define D_DIM  256
#define P_DIM  4
#define N_TOT  4096        // 2*B
#define EPS_F  1e-8f
#define NB     512         // buckets over ld in [0,4): width 1/128
#define BSCALE 128.0f

typedef short  s16x8 __attribute__((ext_vector_type(8)));
typedef float  f32x4 __attribute__((ext_vector_type(4)));

__device__ __forceinline__ void async_load16(const void* g, const void* l) {
    __builtin_amdgcn_global_load_lds(
        (const __attribute__((address_space(1))) unsigned int*)g,
        (__attribute__((address_space(3))) unsigned int*)l,
        16, 0, 0);
}

__device__ __forceinline__ unsigned short f2bf(float x) {
    unsigned int b = __float_as_uint(x);
    b += 0x7FFFu + ((b >> 16) & 1u);        // RNE
    return (unsigned short)(b >> 16);
}

// ---------------- Kernel A: row-normalize features -> bf16 ----------------
__global__ __launch_bounds__(64) void normalize_kernel(
    const float* __restrict__ z_i, const float* __restrict__ z_j,
    unsigned short* __restrict__ fb)
{
    int row  = blockIdx.x;
    int lane = threadIdx.x;
    const float* src = (row < B_SZ) ? (z_i + (size_t)row * D_DIM)
                                    : (z_j + (size_t)(row - B_SZ) * D_DIM);
    float4 v = ((const float4*)src)[lane];
    float ss = v.x*v.x + v.y*v.y + v.z*v.z + v.w*v.w;
    #pragma unroll
    for (int off = 32; off > 0; off >>= 1)
        ss += __shfl_down(ss, off, 64);
    ss = __shfl(ss, 0, 64);
    float inv = 1.0f / sqrtf(ss);
    ushort4 o;
    o.x = f2bf(v.x * inv); o.y = f2bf(v.y * inv);
    o.z = f2bf(v.z * inv); o.w = f2bf(v.w * inv);
    ((ushort4*)(fb + (size_t)row * D_DIM))[lane] = o;
}

// ---- Fused kernel: 16 rows/block; MFMA logits + histogram CDF, no logits in HBM ----
// Waves 0-3: stage B chunks (64 cols, k-chunked [kc][col][32] layout, dbuf) + MFMA
//            with A held in registers. Waves 4-7: epilogue of previous chunk
//            (exp, L1-dist bucket, padded LDS-atomic hists). One barrier per chunk.
#define PHYS4(j) (*(const float4*)(((j) < B_SZ) ? (physics_i + (size_t)(j) * 4) \
                                                : (physics_j + (size_t)((j) - B_SZ) * 4)))

__global__ __launch_bounds__(512, 2) void fused_kernel(
    const unsigned short* __restrict__ fb,
    const float* __restrict__ physics_i, const float* __restrict__ physics_j,
    float* __restrict__ rowres)
{
    __shared__ unsigned short Atile[8 * 16 * 32];      // 8 KB  [kc][row][32]
    __shared__ unsigned short Btile[2][8 * 64 * 32];   // 64 KB [kc][col][32], dbuf
    __shared__ float    accb[2][4][256];               // 8 KB acc handoff (dbuf)
    __shared__ float    bs[16][NB + 8];                // 33.3 KB padded e-sum hists
    __shared__ unsigned cw[16][NB / 2 + 8];            // 16.9 KB padded count hists
    __shared__ float    scr[64];                       // sum_lo partials

    const int tid   = threadIdx.x;
    const int w     = tid >> 6;                     // wave 0..7
    const int L     = tid & 63;
    const int lane  = L;
    const int rowg0 = blockIdx.x * 16;

    // A staging: wave w stages k-chunk w (16 rows x 64 B)
    async_load16(fb + (size_t)(rowg0 + (L >> 2)) * D_DIM + w * 32 + (L & 3) * 8,
                 Atile + w * 512 + L * 8);
    // B chunk-0 staging: wave w (0-3) stages k-chunks 2w, 2w+1
    if (w < 4) {
        #pragma unroll
        for (int kk = 0; kk < 2; ++kk) {
            int kc = w * 2 + kk;
            #pragma unroll
            for (int c4 = 0; c4 < 4; ++c4)
                async_load16(fb + (size_t)(c4 * 16 + (L >> 2)) * D_DIM + kc * 32 + (L & 3) * 8,
                             &Btile[0][kc * 2048 + c4 * 512 + L * 8]);
        }
    }
    // zero histograms (flat, padding included)
    {
        float* p = &bs[0][0];
        for (int t = tid; t < 16 * (NB + 8); t += 512) p[t] = 0.f;
        unsigned* q = &cw[0][0];
        for (int t = tid; t < 16 * (NB / 2 + 8); t += 512) q[t] = 0u;
    }
    __syncthreads();                                // A + B0 staged, zeros visible

    // gemm waves: A fragments to registers (held whole kernel)
    s16x8 afr[8];
    if (w < 4) {
        #pragma unroll
        for (int ks = 0; ks < 8; ++ks)
            afr[ks] = *(const s16x8*)&Atile[ks * 512 + (L & 15) * 32 + (L >> 4) * 8];
    }
    // epilogue waves: anchor labels for their 4 rows
    float4 Li4[4];
    float  sl[4] = {0.f, 0.f, 0.f, 0.f};
    if (w >= 4) {
        #pragma unroll
        for (int q = 0; q < 4; ++q)
            Li4[q] = PHYS4(rowg0 + (L >> 4) * 4 + q);
    }

#define EPILOGUE(PC)                                                          \
    {                                                                         \
        int we = w - 4;                                                       \
        f32x4 a4 = *(const f32x4*)&accb[(PC) & 1][we][L * 4];                 \
        int colg = (PC) * 64 + we * 16 + (L & 15);                            \
        float4 Lj = PHYS4(colg);                                              \
        int rbase = (L >> 4) * 4;                                             \
        _Pragma("unroll")                                                     \
        for (int q = 0; q < 4; ++q) {                                         \
            float l = a4[q] * 0.5f;                    /* /TEMPERATURE */     \
            if (colg != rowg0 + rbase + q) {                                  \
                float d = fabsf(Li4[q].x - Lj.x) + fabsf(Li4[q].y - Lj.y)     \
                        + fabsf(Li4[q].z - Lj.z) + fabsf(Li4[q].w - Lj.w);    \
                int b = (int)(d * BSCALE); if (b > NB - 1) b = NB - 1;        \
                atomicAdd(&bs[rbase + q][b], __expf(l));                      \
                atomicAdd(&cw[rbase + q][b >> 1], 1u << ((b & 1) * 16));      \
                sl[q] += l;                                                   \
            }                                                                 \
        }                                                                     \
    }

    for (int c = 0; c < 64; ++c) {
        if (w < 4) {
            int buf = c & 1;
            if (c + 1 < 64) {                       // prefetch next B chunk
                const unsigned short* gb = fb + (size_t)(c + 1) * 64 * D_DIM;
                #pragma unroll
                for (int kk = 0; kk < 2; ++kk) {
                    int kc = w * 2 + kk;
                    #pragma unroll
                    for (int c4 = 0; c4 < 4; ++c4)
                        async_load16(gb + (size_t)(c4 * 16 + (L >> 2)) * D_DIM + kc * 32 + (L & 3) * 8,
                                     &Btile[buf ^ 1][kc * 2048 + c4 * 512 + L * 8]);
                }
            }
            f32x4 acc = {0.f, 0.f, 0.f, 0.f};
            #pragma unroll
            for (int ks = 0; ks < 8; ++ks) {
                s16x8 bfr = *(const s16x8*)
                    &Btile[buf][ks * 2048 + (w * 16 + (L & 15)) * 32 + (L >> 4) * 8];
                acc = __builtin_amdgcn_mfma_f32_16x16x32_bf16(afr[ks], bfr, acc, 0, 0, 0);
            }
            *(f32x4*)&accb[buf][w][L * 4] = acc;
        } else if (c > 0) {
            EPILOGUE(c - 1);
        }
        __syncthreads();
    }
    if (w >= 4) {
        EPILOGUE(63);
        // reduce sum_lo within 16-lane groups, store partials scr[we*16 + row]
        #pragma unroll
        for (int off = 8; off > 0; off >>= 1) {
            #pragma unroll
            for (int q = 0; q < 4; ++q) sl[q] += __shfl_down(sl[q], off, 16);
        }
        if ((L & 15) == 0) {
            #pragma unroll
            for (int q = 0; q < 4; ++q)
                scr[(w - 4) * 16 + (L >> 4) * 4 + q] = sl[q];
        }
    }
    __syncthreads();                                // hists + scr complete

    // per-row suffix scan + logsum; wave w handles rows 2w, 2w+1
    #pragma unroll
    for (int rr = 0; rr < 2; ++rr) {
        int row = w * 2 + rr;
        float v[8], T[8];
        #pragma unroll
        for (int j = 0; j < 8; ++j) v[j] = bs[row][j * 64 + lane];
        #pragma unroll
        for (int j = 0; j < 8; ++j) {
            float s = v[j];
            #pragma unroll
            for (int off = 1; off < 64; off <<= 1) {
                float u = __shfl_down(s, off, 64);
                if (lane + off < 64) s += u;
            }
            v[j] = s;                               // in-wave inclusive suffix
            T[j] = __shfl(s, 0, 64);                // slice total
        }
        float hi = 0.f, logsum = 0.f;
        #pragma unroll
        for (int j = 7; j >= 0; --j) {
            float S = v[j] + hi;                    // inclusive suffix at bucket j*64+lane
            hi += T[j];
            unsigned cword = cw[row][j * 32 + (lane >> 1)];
            float cnt = (float)((cword >> ((lane & 1) * 16)) & 0xFFFFu);
            logsum = fmaf(cnt, __logf(S + EPS_F), logsum);
        }
        #pragma unroll
        for (int off = 32; off > 0; off >>= 1)
            logsum += __shfl_down(logsum, off, 64);
        if (lane == 0) {
            float slo = scr[row] + scr[16 + row] + scr[32 + row] + scr[48 + row];
            rowres[rowg0 + row] = logsum - slo;
        }
    }
#undef EPILOGUE
}

// ---------------- Kernel D: final reduce ----------------
__global__ __launch_bounds__(256) void final_kernel(
    const float* __restrict__ rowres, float* __restrict__ out)
{
    __shared__ float red[4];
    int tid = threadIdx.x;
    float s = 0.f;
    for (int i = tid; i < N_TOT; i += 256) s += rowres[i];
    #pragma unroll
    for (int off = 32; off > 0; off >>= 1)
        s += __shfl_down(s, off, 64);
    if ((tid & 63) == 0) red[tid >> 6] = s;
    __syncthreads();
    if (tid == 0) {
        double tot = (double)red[0] + red[1] + red[2] + red[3];
        out[0] = (float)(tot / ((double)N_TOT * (N_TOT - 1)));
    }
}

extern "C" void kernel_launch(void* const* d_in, const int* in_sizes, int n_in,
                              void* d_out, int out_size, void* d_ws, size_t ws_size,
                              hipStream_t stream)
{
    const float* z_i  = (const float*)d_in[0];
    const float* z_j  = (const float*)d_in[1];
    const float* ph_i = (const float*)d_in[2];
    const float* ph_j = (const float*)d_in[3];

    unsigned short* fb     = (unsigned short*)d_ws;                 // 2 MB bf16
    float*          rowres = (float*)(fb + (size_t)N_TOT * D_DIM);  // 16 KB

    normalize_kernel<<<N_TOT, 64, 0, stream>>>(z_i, z_j, fb);
    fused_kernel<<<N_TOT / 16, 512, 0, stream>>>(fb, ph_i, ph_j, rowres);
    final_kernel<<<1, 256, 0, stream>>>(rowres, (float*)d_out);
}

// Round 12
// 187.314 us; speedup vs baseline: 1.1874x; 1.0713x over previous
//
#include <hip/hip_runtime.h>
#include <hip/hip_fp16.h>
#include <float.h>
#include <math.h>

#define B_SZ   2048
#define D_DIM  256
#define P_DIM  4
#define N_TOT  4096        // 2*B
#define EPS_F  1e-8f
#define NBR    448         // 7*64 buckets over ld in [0,4): width 1/112
#define BSCALER 112.0f

typedef short  s16x8 __attribute__((ext_vector_type(8)));
typedef float  f32x4 __attribute__((ext_vector_type(4)));

__device__ __forceinline__ void async_load16(const void* g, const void* l) {
    __builtin_amdgcn_global_load_lds(
        (const __attribute__((address_space(1))) unsigned int*)g,
        (__attribute__((address_space(3))) unsigned int*)l,
        16, 0, 0);
}

__device__ __forceinline__ unsigned short f2bf(float x) {
    unsigned int b = __float_as_uint(x);
    b += 0x7FFFu + ((b >> 16) & 1u);        // RNE
    return (unsigned short)(b >> 16);
}

#define PHYS4(j) (*(const float4*)(((j) < B_SZ) ? (physics_i + (size_t)(j) * 4) \
                                                : (physics_j + (size_t)((j) - B_SZ) * 4)))

// ---------------- Kernel A: row-normalize features -> bf16 ----------------
__global__ __launch_bounds__(64) void normalize_kernel(
    const float* __restrict__ z_i, const float* __restrict__ z_j,
    unsigned short* __restrict__ fb)
{
    int row  = blockIdx.x;
    int lane = threadIdx.x;
    const float* src = (row < B_SZ) ? (z_i + (size_t)row * D_DIM)
                                    : (z_j + (size_t)(row - B_SZ) * D_DIM);
    float4 v = ((const float4*)src)[lane];
    float ss = v.x*v.x + v.y*v.y + v.z*v.z + v.w*v.w;
    #pragma unroll
    for (int off = 32; off > 0; off >>= 1)
        ss += __shfl_down(ss, off, 64);
    ss = __shfl(ss, 0, 64);
    float inv = 1.0f / sqrtf(ss);
    ushort4 o;
    o.x = f2bf(v.x * inv); o.y = f2bf(v.y * inv);
    o.z = f2bf(v.z * inv); o.w = f2bf(v.w * inv);
    ((ushort4*)(fb + (size_t)row * D_DIM))[lane] = o;
}

// ------- Kernel B: logits = f @ f^T / TEMP, bf16 MFMA, 128x128, LDS dbuf -------
__global__ __launch_bounds__(256, 4) void gemm_kernel(
    const unsigned short* __restrict__ fb, unsigned short* __restrict__ out)
{
    __shared__ unsigned short As[2][128 * 32];   // 16 KB
    __shared__ unsigned short Bs[2][128 * 32];   // 16 KB

    int tid = threadIdx.x;
    int w   = tid >> 6;
    int L   = tid & 63;
    int bm  = blockIdx.y * 128;
    int bn  = blockIdx.x * 128;

    f32x4 acc[4][4];
    #pragma unroll
    for (int r = 0; r < 4; ++r)
        #pragma unroll
        for (int c = 0; c < 4; ++c)
            #pragma unroll
            for (int q = 0; q < 4; ++q) acc[r][c][q] = 0.f;

    const int wr = (w >> 1) * 64;
    const int wc = (w & 1) * 64;
    const int rowbase = (w < 2) ? (bm + w * 64) : (bn + (w - 2) * 64);
    const int lcol    = (L & 3) * 8;

    #define STAGE(buf, k0)                                                     \
        {                                                                      \
            unsigned short* lchunk = (w < 2) ? (As[buf] + w * 2048)            \
                                             : (Bs[buf] + (w - 2) * 2048);     \
            _Pragma("unroll")                                                  \
            for (int c = 0; c < 4; ++c) {                                      \
                int grow = rowbase + c * 16 + (L >> 2);                        \
                const unsigned short* g =                                      \
                    fb + (size_t)grow * D_DIM + (k0) + lcol;                   \
                async_load16(g, lchunk + c * 512);                             \
            }                                                                  \
        }

    STAGE(0, 0);

    #pragma unroll
    for (int it = 0; it < 8; ++it) {
        __syncthreads();
        if (it < 7) STAGE((it + 1) & 1, (it + 1) * 32);

        int buf  = it & 1;
        int koff = (L >> 4) * 8;
        s16x8 a[4], b[4];
        #pragma unroll
        for (int rt = 0; rt < 4; ++rt)
            a[rt] = *(const s16x8*)(As[buf] + (wr + rt * 16 + (L & 15)) * 32 + koff);
        #pragma unroll
        for (int ct = 0; ct < 4; ++ct)
            b[ct] = *(const s16x8*)(Bs[buf] + (wc + ct * 16 + (L & 15)) * 32 + koff);
        #pragma unroll
        for (int rt = 0; rt < 4; ++rt)
            #pragma unroll
            for (int ct = 0; ct < 4; ++ct)
                acc[rt][ct] = __builtin_amdgcn_mfma_f32_16x16x32_bf16(
                    a[rt], b[ct], acc[rt][ct], 0, 0, 0);
    }
    #undef STAGE

    #pragma unroll
    for (int rt = 0; rt < 4; ++rt) {
        #pragma unroll
        for (int ct = 0; ct < 4; ++ct) {
            int col = bn + wc + ct * 16 + (L & 15);
            #pragma unroll
            for (int q = 0; q < 4; ++q) {
                int row = bm + wr + rt * 16 + (L >> 4) * 4 + q;
                out[(size_t)row * N_TOT + col] = f2bf(acc[rt][ct][q] * 0.5f); // /TEMP
            }
        }
    }
}

// ---- Kernel C: 4 rows/block; labels staged in LDS (f16x4); per-row e-hist CDF ----
// denom_j ~= inclusive suffix over buckets >= bucket(ld_j). f16 labels jitter bucket
// edges by <=1/16 bucket width; total loss error ~4e-3 << 0.146 threshold.
__global__ __launch_bounds__(256, 4) void row_kernel(
    const unsigned short* __restrict__ logits,
    const float* __restrict__ physics_i, const float* __restrict__ physics_j,
    float* __restrict__ rowres)
{
    __shared__ __half2 lbl[N_TOT][2];        // 32 KB f16x4 labels
    __shared__ float   bs[4][NBR];           // 7 KB e-sum hists (-> suffix S)
    __shared__ float   scr[32];              // wave partials

    const int tid  = threadIdx.x;
    const int lane = tid & 63;
    const int wid  = tid >> 6;
    const int i0   = blockIdx.x * 4;

    // zero hists (4*448 = 1792 floats)
    for (int t = tid; t < 4 * NBR; t += 256) ((float*)bs)[t] = 0.f;

    // stage labels -> LDS f16x4 (coalesced f32x4 global reads)
    #pragma unroll
    for (int t = 0; t < 16; ++t) {
        int j = tid + t * 256;
        float4 L = PHYS4(j);
        lbl[j][0] = __floats2half2_rn(L.x, L.y);
        lbl[j][1] = __floats2half2_rn(L.z, L.w);
    }
    // anchors (converted identically so self-distance is exactly 0)
    __half2 A01[4], A23[4];
    #pragma unroll
    for (int r = 0; r < 4; ++r) {
        float4 L = PHYS4(i0 + r);
        A01[r] = __floats2half2_rn(L.x, L.y);
        A23[r] = __floats2half2_rn(L.z, L.w);
    }
    __syncthreads();                                   // B0: labels + zeros ready

    const unsigned short* lg = logits + (size_t)i0 * N_TOT;

    // phase 1: per element (j interleaved), 4 rows amortized per label read
    unsigned pb01[16], pb23[16];
    float sl[4] = {0.f, 0.f, 0.f, 0.f};
    #pragma unroll 2
    for (int t = 0; t < 16; ++t) {
        int j = tid + t * 256;
        __half2 x01 = lbl[j][0];
        __half2 x23 = lbl[j][1];
        float l[4];
        #pragma unroll
        for (int r = 0; r < 4; ++r)
            l[r] = __uint_as_float((unsigned)lg[(size_t)r * N_TOT + j] << 16);
        int b[4];
        #pragma unroll
        for (int r = 0; r < 4; ++r) {
            __half2 d0 = __habs2(__hsub2(x01, A01[r]));
            __half2 d1 = __habs2(__hsub2(x23, A23[r]));
            __half2 dd = __hadd2(d0, d1);
            float d = __low2float(dd) + __high2float(dd);
            int bb = (int)(d * BSCALER);
            if (bb > NBR - 1) bb = NBR - 1;
            b[r] = bb;
            bool diag = (j == i0 + r);
            float e = diag ? 0.f : __expf(l[r]);
            sl[r] += diag ? 0.f : l[r];
            atomicAdd(&bs[r][bb], e);
        }
        pb01[t] = (unsigned)b[0] | ((unsigned)b[1] << 16);
        pb23[t] = (unsigned)b[2] | ((unsigned)b[3] << 16);
    }
    #pragma unroll
    for (int off = 32; off > 0; off >>= 1)
        #pragma unroll
        for (int r = 0; r < 4; ++r) sl[r] += __shfl_down(sl[r], off, 64);
    if (lane == 0)
        #pragma unroll
        for (int r = 0; r < 4; ++r) scr[r * 4 + wid] = sl[r];
    __syncthreads();                                   // B1: hists + sl ready

    // phase 2: wave w computes inclusive suffix of hist row w (7 slices of 64)
    {
        int r = wid;
        float v[7], T[7];
        #pragma unroll
        for (int k = 0; k < 7; ++k) v[k] = bs[r][k * 64 + lane];
        #pragma unroll
        for (int k = 0; k < 7; ++k) {
            float s = v[k];
            #pragma unroll
            for (int off = 1; off < 64; off <<= 1) {
                float u = __shfl_down(s, off, 64);
                if (lane + off < 64) s += u;
            }
            v[k] = s;                                  // in-slice inclusive suffix
            T[k] = __shfl(s, 0, 64);                   // slice total
        }
        float hi = 0.f;
        #pragma unroll
        for (int k = 6; k >= 0; --k) {
            bs[r][k * 64 + lane] = v[k] + hi;          // global inclusive suffix S
            hi += T[k];
        }
    }
    __syncthreads();                                   // B2: S ready

    // phase 3: per-element denom lookup + log (independent scattered LDS reads)
    float ls[4] = {0.f, 0.f, 0.f, 0.f};
    #pragma unroll 2
    for (int t = 0; t < 16; ++t) {
        int j = tid + t * 256;
        int b0 = pb01[t] & 0xFFFFu, b1 = pb01[t] >> 16;
        int b2 = pb23[t] & 0xFFFFu, b3 = pb23[t] >> 16;
        float S0 = bs[0][b0], S1 = bs[1][b1], S2 = bs[2][b2], S3 = bs[3][b3];
        if (j != i0 + 0) ls[0] += __logf(S0 + EPS_F);
        if (j != i0 + 1) ls[1] += __logf(S1 + EPS_F);
        if (j != i0 + 2) ls[2] += __logf(S2 + EPS_F);
        if (j != i0 + 3) ls[3] += __logf(S3 + EPS_F);
    }
    #pragma unroll
    for (int off = 32; off > 0; off >>= 1)
        #pragma unroll
        for (int r = 0; r < 4; ++r) ls[r] += __shfl_down(ls[r], off, 64);
    if (lane == 0)
        #pragma unroll
        for (int r = 0; r < 4; ++r) scr[16 + r * 4 + wid] = ls[r];
    __syncthreads();                                   // B3
    if (tid < 4) {
        int r = tid;
        float slo = scr[r * 4] + scr[r * 4 + 1] + scr[r * 4 + 2] + scr[r * 4 + 3];
        float lst = scr[16 + r * 4] + scr[16 + r * 4 + 1]
                  + scr[16 + r * 4 + 2] + scr[16 + r * 4 + 3];
        rowres[i0 + r] = lst - slo;
    }
}

// ---------------- Kernel D: final reduce ----------------
__global__ __launch_bounds__(256) void final_kernel(
    const float* __restrict__ rowres, float* __restrict__ out)
{
    __shared__ float red[4];
    int tid = threadIdx.x;
    float s = 0.f;
    for (int i = tid; i < N_TOT; i += 256) s += rowres[i];
    #pragma unroll
    for (int off = 32; off > 0; off >>= 1)
        s += __shfl_down(s, off, 64);
    if ((tid & 63) == 0) red[tid >> 6] = s;
    __syncthreads();
    if (tid == 0) {
        double tot = (double)red[0] + red[1] + red[2] + red[3];
        out[0] = (float)(tot / ((double)N_TOT * (N_TOT - 1)));
    }
}

extern "C" void kernel_launch(void* const* d_in, const int* in_sizes, int n_in,
                              void* d_out, int out_size, void* d_ws, size_t ws_size,
                              hipStream_t stream)
{
    const float* z_i  = (const float*)d_in[0];
    const float* z_j  = (const float*)d_in[1];
    const float* ph_i = (const float*)d_in[2];
    const float* ph_j = (const float*)d_in[3];

    unsigned short* fb     = (unsigned short*)d_ws;                 // 2 MB bf16
    unsigned short* logits = fb + (size_t)N_TOT * D_DIM;            // 32 MB bf16
    float*          rowres = (float*)(logits + (size_t)N_TOT * N_TOT);

    normalize_kernel<<<N_TOT, 64, 0, stream>>>(z_i, z_j, fb);
    dim3 g(N_TOT / 128, N_TOT / 128);
    gemm_kernel<<<g, 256, 0, stream>>>(fb, logits);
    row_kernel<<<N_TOT / 4, 256, 0, stream>>>(logits, ph_i, ph_j, rowres);
    final_kernel<<<1, 256, 0, stream>>>(rowres, (float*)d_out);
}